// Round 12
// baseline (702.410 us; speedup 1.0000x reference)
//
#include <hip/hip_runtime.h>
#include <cstdint>

// ---------------------------------------------------------------------------
// PlanningNetwork fused kernel for MI355X (gfx950).  B=16384,S=128,H=128,E=64,T=32.
// R12: R11 with the quality-L1 tile-count bug fixed (needs 16 tiles = 2 Mx8 N;
//      R11 only issued 8, leaving QL1 cols 64..127 as garbage -> plan_quality
//      absmax 0.5). Structure: 512 blocks x 32 rows, 2 blocks/CU -> the two
//      co-resident blocks barrier independently so cell-update VALU (the
//      measured ~190us dominant term) overlaps the other block's gemm/stream.
// ---------------------------------------------------------------------------

typedef unsigned short u16;
typedef unsigned int   u32;
typedef float f32x4 __attribute__((ext_vector_type(4)));
typedef short s16x8 __attribute__((ext_vector_type(8)));
typedef int   i32x4 __attribute__((ext_vector_type(4)));

__device__ __forceinline__ u16 f2bf(float x) {
  u32 u = __float_as_uint(x);
  u32 r = u + 0x7fffu + ((u >> 16) & 1u);   // RNE
  return (u16)(r >> 16);
}
__device__ __forceinline__ float bf2f(u16 v) { return __uint_as_float(((u32)v) << 16); }
__device__ __forceinline__ float fexp2(float x) { return __builtin_amdgcn_exp2f(x); }
__device__ __forceinline__ float frcp(float x)  { return __builtin_amdgcn_rcpf(x); }
__device__ __forceinline__ float sigf(float x)  { return frcp(1.f + fexp2(-1.4426950408889634f * x)); }
__device__ __forceinline__ float tanh_(float x) { return 1.f - 2.f * frcp(1.f + fexp2(2.8853900817779268f * x)); }

struct KParams {
  const float* gc;
  const float *W1, *b1, *W2, *b2, *W3, *b3;
  const float *Wih1, *bih1, *Whh1, *bhh1;
  const float *Wih2, *bih2, *Whh2, *bhh2;
  const float *Wq1, *bq1, *Wq2, *bq2, *Wq3, *bq3;
  const float *Wp1, *bp1, *Wp2, *bp2;
  const float *Wd1, *bd1, *Wd2, *bd2;
  const float *Wc1, *bc1, *Wc2, *bc2;
};

// bf16 workspace element offsets (encoder/heads/quality only)
#define OW1   0
#define OW2   32768
#define OW3   65536
#define OWQ1  73728
#define OWQ2  106496
#define OWP1  114688
#define OWP2  116736
#define OWD1  117248
#define OWD2  119296
#define OWC1  119808
#define OWC2  121856
#define NBF16 122368
// byte offsets for i8 LSTM weights and fp32 scale/bias area
#define OWL1_B 245760
#define OWL2_B 376832
#define OFP32_B 507904   // fp32: bl1[512] bl2[512] dq1[512] dq2[512]

// ---------------------------------------------------------------------------
// Prep A: bf16 weights (encoder/heads/quality) + combined LSTM biases.
// ---------------------------------------------------------------------------
__global__ void prep_bf16(KParams P, u16* __restrict__ wsb, float* __restrict__ wsf) {
  int i = blockIdx.x * blockDim.x + threadIdx.x;
  int stride = gridDim.x * blockDim.x;
  for (; i < NBF16 + 1024; i += stride) {
    if (i < NBF16) {
      float v;
      int idx = i;
      if (idx < 32768) v = P.W1[idx];                                   // [256][128]
      else if ((idx -= 32768) < 32768) v = P.W2[idx];                   // [128][256]
      else if ((idx -= 32768) < 8192)  v = P.W3[idx];                   // [64][128]
      else if ((idx -= 8192) < 32768) {                                 // Wq1 padded to K=256
        int n = idx >> 8, k = idx & 255;
        v = (k < 192) ? P.Wq1[n * 192 + k] : 0.f;
      }
      else if ((idx -= 32768) < 8192) v = P.Wq2[idx];                   // [64][128]
      else if ((idx -= 8192) < 2048)  v = P.Wp1[idx];                   // [32][64]
      else if ((idx -= 2048) < 512) { int n = idx >> 5, k = idx & 31; v = (n < 8) ? P.Wp2[n * 32 + k] : 0.f; }
      else if ((idx -= 512) < 2048)  v = P.Wd1[idx];
      else if ((idx -= 2048) < 512) { int n = idx >> 5, k = idx & 31; v = (n < 1) ? P.Wd2[k] : 0.f; }
      else if ((idx -= 512) < 2048)  v = P.Wc1[idx];
      else { idx -= 2048; int n = idx >> 5, k = idx & 31; v = (n < 1) ? P.Wc2[k] : 0.f; }
      wsb[i] = f2bf(v);
    } else {
      int idx = i - NBF16;          // 0..1023 : combined permuted LSTM biases
      int l = idx >> 9, n = idx & 511;
      int gate = (n >> 4) & 3, j = ((n >> 6) << 4) | (n & 15);
      int orig = gate * 128 + j;
      wsf[idx] = (l == 0) ? (P.bih1[orig] + P.bhh1[orig]) : (P.bih2[orig] + P.bhh2[orig]);
    }
  }
}

// ---------------------------------------------------------------------------
// Prep B: LSTM i8 weights, one wave per output row (1024 rows).
// ---------------------------------------------------------------------------
__global__ void prep_lstm_q(KParams P, char* __restrict__ wsbytes, float* __restrict__ wsf) {
  int n = blockIdx.x;        // 0..1023
  int lane = threadIdx.x;    // 0..63
  int l = n >> 9, nn = n & 511;
  int gate = (nn >> 4) & 3, j = ((nn >> 6) << 4) | (nn & 15);
  int orig = gate * 128 + j;
  float v[4];
#pragma unroll
  for (int i = 0; i < 4; ++i) {
    int k = lane * 4 + i;
    if (l == 0) v[i] = (k < 128) ? P.Wih1[orig * 128 + k] : P.Whh1[orig * 128 + (k - 128)];
    else        v[i] = (k < 128) ? P.Whh2[orig * 128 + k] : P.Wih2[orig * 128 + (k - 128)];
  }
  float m = fmaxf(fmaxf(fabsf(v[0]), fabsf(v[1])), fmaxf(fabsf(v[2]), fabsf(v[3])));
  for (int off = 1; off < 64; off <<= 1) m = fmaxf(m, __shfl_xor(m, off));
  float inv = (m > 1e-30f) ? 127.f / m : 0.f;
  u32 pk = 0;
#pragma unroll
  for (int i = 0; i < 4; ++i) {
    int q = (int)rintf(v[i] * inv);
    q = max(-127, min(127, q));
    pk |= ((u32)(q & 255)) << (8 * i);
  }
  *(u32*)(wsbytes + (l ? OWL2_B : OWL1_B) + nn * 256 + lane * 4) = pk;
  if (lane == 0) wsf[1024 + l * 512 + nn] = (m > 1e-30f) ? (m * (1.f / (127.f * 127.f))) : 0.f;
}

// ---------------------------------------------------------------------------
// LDS write helper (bf16 panels) with per-row 16B-slot rotation.
// ---------------------------------------------------------------------------
__device__ __forceinline__ void lds_wr_bf16(char* sD, int stride, int mask, int m, int n, float v) {
  int slot = ((n >> 3) + m) & mask;
  *(u16*)(sD + m * stride + (slot << 4) + (n & 7) * 2) = f2bf(v);
}

// Generic LDS-A x global-B bf16 MFMA tile loop, 32-row M (2 M-tiles).
// tile id: mt = tile & 1, nt = tile >> 1.  NTILES = 2 * (N/16).
template <int K, int STRIDE, int MASK, int NTILES, class EPI>
__device__ __forceinline__ void gemm_generic(const char* sA, const u16* W,
                                             int w, int l16, int grp, EPI epi) {
  constexpr int KT = K / 32;
  constexpr int ITMAX = (NTILES + 7) / 8;
#pragma unroll
  for (int it = 0; it < ITMAX; ++it) {
    int tile = w + it * 8;
    if (tile < NTILES) {
      int mt = tile & 1, nt = tile >> 1;
      int row = mt * 16 + l16;
      const u16* wl = W + (size_t)(nt * 16 + l16) * K + grp * 8;
      f32x4 acc = (f32x4){0.f, 0.f, 0.f, 0.f};
#pragma unroll
      for (int kt = 0; kt < KT; ++kt) {
        int slot = (kt * 4 + grp + row) & MASK;
        s16x8 a = *(const s16x8*)(sA + row * STRIDE + (slot << 4));
        s16x8 b = *(const s16x8*)(wl + kt * 32);
        acc = __builtin_amdgcn_mfma_f32_16x16x32_bf16(a, b, acc, 0, 0, 0);
      }
      epi(it, mt, nt, acc);
    }
  }
}

// ---------------------------------------------------------------------------
// LSTM i8 pieces. Half-panels [32 rows][128 i8] = [32][128B], 8 slots rot.
// ---------------------------------------------------------------------------
__device__ __forceinline__ void ldb4q(const char* const (&wb)[4], int kt, i32x4 (&bd)[4]) {
#pragma unroll
  for (int g = 0; g < 4; ++g) bd[g] = *(const i32x4*)(wb[g] + kt * 64);
}

__device__ __forceinline__ void zacc_i(i32x4 (&acc)[2][4]) {
#pragma unroll
  for (int a = 0; a < 2; ++a)
#pragma unroll
    for (int b = 0; b < 4; ++b) acc[a][b] = (i32x4){0, 0, 0, 0};
}

// kt in [KT0,KT1) of 4 (K=64 each): kt<2 reads X half, kt>=2 reads H half.
template <int KT0, int KT1>
__device__ __forceinline__ void lstm_gemm_i8(const char* X, const char* Hh,
                                             const int (&ha)[2][2],
                                             const char* const (&wb)[4],
                                             const i32x4 (&bpre)[4],
                                             i32x4 (&acc)[2][4]) {
  i32x4 bc[4], bn[4], ac[2], an[2];
#pragma unroll
  for (int g = 0; g < 4; ++g) bc[g] = bpre[g];
  {
    const char* base = (KT0 < 2) ? X : Hh;
#pragma unroll
    for (int mt = 0; mt < 2; ++mt) ac[mt] = *(const i32x4*)(base + ha[mt][KT0 & 1]);
  }
#pragma unroll
  for (int kt = KT0; kt < KT1; ++kt) {
    if (kt + 1 < KT1) {
      ldb4q(wb, kt + 1, bn);
      const char* base = (kt + 1 < 2) ? X : Hh;
#pragma unroll
      for (int mt = 0; mt < 2; ++mt) an[mt] = *(const i32x4*)(base + ha[mt][(kt + 1) & 1]);
    }
#pragma unroll
    for (int mt = 0; mt < 2; ++mt)
#pragma unroll
      for (int g = 0; g < 4; ++g)
        acc[mt][g] = __builtin_amdgcn_mfma_i32_16x16x64_i8(ac[mt], bc[g], acc[mt][g], 0, 0, 0);
    if (kt + 1 < KT1) {
#pragma unroll
      for (int g = 0; g < 4; ++g) bc[g] = bn[g];
#pragma unroll
      for (int mt = 0; mt < 2; ++mt) ac[mt] = an[mt];
    }
  }
}

// Update: dequant + cell + write i8 h to dst panel (or bf16 to qbuf if FINAL).
// LAYER 1 also stores h2 to out0 (inline scalar NT — best measured config, R6).
template <int LAYER, bool FINAL>
__device__ __forceinline__ void lstm_update_i8(const i32x4 (&acc)[2][4], float (&cst)[2][4],
                                               const float (&bl)[4], const float (&dq)[4],
                                               float dqmul, char* dst, char* qbuf,
                                               int w, int l16, int grp,
                                               float* __restrict__ out0, int b0, int t) {
  const int j = w * 16 + l16;
  float dqe[4];
#pragma unroll
  for (int g = 0; g < 4; ++g) dqe[g] = dq[g] * dqmul;
#pragma unroll
  for (int mt = 0; mt < 2; ++mt) {
#pragma unroll
    for (int r = 0; r < 4; ++r) {
      const int m = mt * 16 + grp * 4 + r;
      float gi = (float)acc[mt][0][r] * dqe[0] + bl[0];
      float gf = (float)acc[mt][1][r] * dqe[1] + bl[1];
      float gg = (float)acc[mt][2][r] * dqe[2] + bl[2];
      float go = (float)acc[mt][3][r] * dqe[3] + bl[3];
      float c = sigf(gf) * cst[mt][r] + sigf(gi) * tanh_(gg);
      cst[mt][r] = c;
      float h = sigf(go) * tanh_(c);
      if (!FINAL) {
        int q = (int)rintf(h * 127.f);   // |h| < 1 strictly -> no clamp needed
        *(char*)(dst + m * 128 + ((((j >> 4) + m) & 7) << 4) + (j & 15)) = (char)q;
      } else {
        *(u16*)(qbuf + m * 256 + ((((j >> 3) + m) & 15) << 4) + (j & 7) * 2) = f2bf(h);
      }
      if (LAYER == 1)
        __builtin_nontemporal_store(h, &out0[(size_t)(b0 + m) * 4096 + (size_t)t * 128 + j]);
    }
  }
}

// ---------------------------------------------------------------------------
// Fused main kernel: 512 blocks x 512 threads, 32 batch rows per block,
// 2 blocks/CU (independent barriers -> VALU/MFMA/mem phase overlap).
// LDS (36KB) phase aliasing:
//   encoder: bufA=[0,16K)  GCB/EL2=[16K,24K)
//   heads:   htmp=[24K,30K)
//   ctx:     CTXB bf16 [32K,36K)  (persists to quality)
//   LSTM:    X0=[0,4K) X1=[4K,8K) H10=[8K,12K) H11=[12K,16K)  (i8)
//            QBUF bf16 [24K,32K) written at t=31 only
//   quality: QL1=[0,8K) QL2=[8K,12K)
// ---------------------------------------------------------------------------
__global__ __launch_bounds__(512, 4) void planning_fused(KParams P,
                                                         const u16* __restrict__ wsb,
                                                         const char* __restrict__ wsbytes,
                                                         const float* __restrict__ wsf,
                                                         float* __restrict__ out) {
  __shared__ __align__(16) char smem[36864];
  char* bufA = smem;              // 16KB [32][512B] rot-32
  char* GCB  = smem + 16384;      // 8KB  [32][256B] rot-16 (gc, then EL2)
  char* htmp = smem + 24576;      // 6KB  3 x [32][64B]
  char* X0   = smem;
  char* X1   = smem + 4096;
  char* H10  = smem + 8192;
  char* H11  = smem + 12288;
  char* QBUF = smem + 24576;      // 8KB [32][256B]
  char* CTXB = smem + 32768;      // 4KB [32][128B]
  char* QL1  = smem;              // 8KB
  char* QL2  = smem + 8192;       // 4KB

  const int tid = threadIdx.x;
  const int lane = tid & 63;
  const int w = tid >> 6;
  const int l16 = lane & 15;
  const int grp = lane >> 4;
  const int b0 = blockIdx.x * 32;

  float* out0 = out;                 // action_sequence (B,32,128)
  float* out1 = out + 67108864;      // plan_quality   (B,1)
  float* out2 = out + 67125248;      // plan_type      (B,8)
  float* out3 = out + 67256320;      // duration       (B,1)
  float* out4 = out + 67272704;      // cost           (B,1)
  float* out5 = out + 67289088;      // ctx            (B,64)

  // ---- stage goal_context -> GCB (bf16, rot-16) ----
#pragma unroll
  for (int ii = 0; ii < 2; ++ii) {
    int idx = tid + ii * 512;                 // 1024 = 32 rows * 32 float4
    int row = idx >> 5, c4 = idx & 31;
    f32x4 v = *(const f32x4*)(P.gc + (size_t)(b0 + row) * 128 + c4 * 4);
    u32 lo = (u32)f2bf(v[0]) | ((u32)f2bf(v[1]) << 16);
    u32 hi = (u32)f2bf(v[2]) | ((u32)f2bf(v[3]) << 16);
    int byte = row * 256 + ((((c4 >> 1) + row) & 15) << 4) + (c4 & 1) * 8;
    uint2 pk; pk.x = lo; pk.y = hi;
    *(uint2*)(GCB + byte) = pk;
  }
  __syncthreads();

  // ---- encoder L1: (32x128)@W1^T -> relu -> bufA (rot-32, stride 512) ----
  gemm_generic<128, 256, 15, 32>(GCB, wsb + OW1, w, l16, grp,
    [&](int, int mt, int nt, f32x4 a) {
      int n = nt * 16 + l16;
      float bias = P.b1[n];
#pragma unroll
      for (int r = 0; r < 4; ++r)
        lds_wr_bf16(bufA, 512, 31, mt * 16 + grp * 4 + r, n, fmaxf(a[r] + bias, 0.f));
    });
  __syncthreads();

  // ---- encoder L2: (32x256)@W2^T -> relu -> EL2 (=GCB region) ----
  gemm_generic<256, 512, 31, 16>(bufA, wsb + OW2, w, l16, grp,
    [&](int, int mt, int nt, f32x4 a) {
      int n = nt * 16 + l16;
      float bias = P.b2[n];
#pragma unroll
      for (int r = 0; r < 4; ++r)
        lds_wr_bf16(GCB, 256, 15, mt * 16 + grp * 4 + r, n, fmaxf(a[r] + bias, 0.f));
    });
  __syncthreads();

  // ---- zero X0 panel (x0 pad); ctx gemm EL2 -> regs ----
  if (tid < 256) *(f32x4*)(X0 + tid * 16) = (f32x4){0.f, 0.f, 0.f, 0.f};   // 4KB
  f32x4 ctx3;
  gemm_generic<128, 256, 15, 8>(GCB, wsb + OW3, w, l16, grp,
    [&](int, int, int, f32x4 a) { ctx3 = a; });
  __syncthreads();

  // ctx epilogue: +b3, -> out5, -> CTXB (bf16) + X0 (i8, scale 63.5)
  {
    int mt = w & 1, nt = w >> 1;
    int n = nt * 16 + l16;
    float bias = P.b3[n];
#pragma unroll
    for (int r = 0; r < 4; ++r) {
      int m = mt * 16 + grp * 4 + r;
      float v = ctx3[r] + bias;
      out5[(size_t)(b0 + m) * 64 + n] = v;
      *(u16*)(CTXB + m * 128 + ((((n >> 3) + m) & 7) << 4) + (n & 7) * 2) = f2bf(v);
      int q = (int)rintf(v * 63.5f);
      q = max(-127, min(127, q));
      *(char*)(X0 + m * 128 + ((((n >> 4) + m) & 7) << 4) + (n & 15)) = (char)q;
    }
  }
  __syncthreads();

  // ---- heads level 1 (plan/dur/cost): relu(ctx@W^T+b) -> htmp ----
#pragma unroll
  for (int hh = 0; hh < 3; ++hh) {
    const u16* Wh = (hh == 0) ? (wsb + OWP1) : (hh == 1) ? (wsb + OWD1) : (wsb + OWC1);
    const float* bh = (hh == 0) ? P.bp1 : (hh == 1) ? P.bd1 : P.bc1;
    char* dsth = htmp + hh * 2048;
    gemm_generic<64, 128, 7, 4>(CTXB, Wh, w, l16, grp,
      [&](int, int mt, int nt, f32x4 a) {
        int n = nt * 16 + l16;
        float bias = bh[n];
#pragma unroll
        for (int r = 0; r < 4; ++r)
          lds_wr_bf16(dsth, 64, 3, mt * 16 + grp * 4 + r, n, fmaxf(a[r] + bias, 0.f));
      });
  }
  __syncthreads();

  // ---- heads level 2: plan softmax / duration / cost (6 tiles, w<6) ----
  if (w < 6) {
    int head = w >> 1, mt = w & 1;
    int row = mt * 16 + l16;
    const char* aB = htmp + head * 2048;
    int slot = (grp + row) & 3;
    s16x8 a = *(const s16x8*)(aB + row * 64 + (slot << 4));
    const u16* W2h = (head == 0) ? (wsb + OWP2) : (head == 1) ? (wsb + OWD2) : (wsb + OWC2);
    s16x8 b = *(const s16x8*)(W2h + l16 * 32 + grp * 8);
    f32x4 acc = (f32x4){0.f, 0.f, 0.f, 0.f};
    acc = __builtin_amdgcn_mfma_f32_16x16x32_bf16(a, b, acc, 0, 0, 0);
    if (head == 0) {
      float bp = (l16 < 8) ? P.bp2[l16] : 0.f;
#pragma unroll
      for (int r = 0; r < 4; ++r) {
        int m = mt * 16 + grp * 4 + r;
        float v = (l16 < 8) ? (acc[r] + bp) : -3.0e38f;
        float mx = v;
        mx = fmaxf(mx, __shfl_xor(mx, 1));
        mx = fmaxf(mx, __shfl_xor(mx, 2));
        mx = fmaxf(mx, __shfl_xor(mx, 4));
        mx = fmaxf(mx, __shfl_xor(mx, 8));
        float e = (l16 < 8) ? fexp2(1.4426950408889634f * (v - mx)) : 0.f;
        float s = e;
        s += __shfl_xor(s, 1); s += __shfl_xor(s, 2);
        s += __shfl_xor(s, 4); s += __shfl_xor(s, 8);
        if (l16 < 8) out2[(size_t)(b0 + m) * 8 + l16] = e * frcp(s);
      }
    } else {
      float bb = (head == 1) ? P.bd2[0] : P.bc2[0];
      float* dst = (head == 1) ? out3 : out4;
      if (l16 == 0) {
#pragma unroll
        for (int r = 0; r < 4; ++r) {
          int m = mt * 16 + grp * 4 + r;
          dst[b0 + m] = fmaxf(acc[r] + bb, 0.f);
        }
      }
    }
  }
  __syncthreads();   // htmp reads done before LSTM (QBUF shares the region)

  // ---- LSTM: 32 steps, 2 layers, i8, 2 barriers/step ----
  int ha[2][2];
#pragma unroll
  for (int mt = 0; mt < 2; ++mt) {
    int row = mt * 16 + l16;
#pragma unroll
    for (int k2 = 0; k2 < 2; ++k2)
      ha[mt][k2] = row * 128 + (((k2 * 4 + grp + row) & 7) << 4);
  }
  const char* wb1[4]; const char* wb2[4];
  float bl1[4], bl2[4], dq1[4], dq2[4];
#pragma unroll
  for (int g = 0; g < 4; ++g) {
    int nn = w * 64 + g * 16 + l16;
    wb1[g] = wsbytes + OWL1_B + (size_t)nn * 256 + grp * 16;
    wb2[g] = wsbytes + OWL2_B + (size_t)nn * 256 + grp * 16;
    bl1[g] = wsf[nn];          bl2[g] = wsf[512 + nn];
    dq1[g] = wsf[1024 + nn];   dq2[g] = wsf[1536 + nn];
  }
  float cst1[2][4], cst2[2][4];
#pragma unroll
  for (int a = 0; a < 2; ++a)
#pragma unroll
    for (int b = 0; b < 4; ++b) { cst1[a][b] = 0.f; cst2[a][b] = 0.f; }

  i32x4 bpre[4];
  ldb4q(wb1, 0, bpre);

  { // t = 0: layer1 reads only X half (ctx scale -> dqmul=2); layer2 only H half.
    i32x4 acc[2][4]; zacc_i(acc);
    lstm_gemm_i8<0, 2>(X0, H10, ha, wb1, bpre, acc);
    i32x4 bq[4]; ldb4q(wb2, 2, bq);
    lstm_update_i8<0, false>(acc, cst1, bl1, dq1, 2.f, H11, QBUF, w, l16, grp, out0, b0, 0);
    __syncthreads();
    zacc_i(acc);
    lstm_gemm_i8<2, 4>(X0, H11, ha, wb2, bq, acc);
    ldb4q(wb1, 0, bpre);
    lstm_update_i8<1, false>(acc, cst2, bl2, dq2, 1.f, X1, QBUF, w, l16, grp, out0, b0, 0);
    __syncthreads();
  }
  for (int t = 1; t < 31; ++t) {
    const char* Xr = (t & 1) ? X1 : X0;
    char*       Xw = (t & 1) ? X0 : X1;
    const char* Hr = (t & 1) ? H11 : H10;
    char*       Hw = (t & 1) ? H10 : H11;
    i32x4 acc[2][4]; zacc_i(acc);
    lstm_gemm_i8<0, 4>(Xr, Hr, ha, wb1, bpre, acc);
    i32x4 bq[4]; ldb4q(wb2, 0, bq);
    lstm_update_i8<0, false>(acc, cst1, bl1, dq1, 1.f, Hw, QBUF, w, l16, grp, out0, b0, t);
    __syncthreads();
    zacc_i(acc);
    lstm_gemm_i8<0, 4>(Xr, Hw, ha, wb2, bq, acc);
    ldb4q(wb1, 0, bpre);
    lstm_update_i8<1, false>(acc, cst2, bl2, dq2, 1.f, Xw, QBUF, w, l16, grp, out0, b0, t);
    __syncthreads();
  }
  { // t = 31 (odd): layer2 writes h2 as bf16 into QBUF for the quality head.
    i32x4 acc[2][4]; zacc_i(acc);
    lstm_gemm_i8<0, 4>(X1, H11, ha, wb1, bpre, acc);
    i32x4 bq[4]; ldb4q(wb2, 0, bq);
    lstm_update_i8<0, false>(acc, cst1, bl1, dq1, 1.f, H10, QBUF, w, l16, grp, out0, b0, 31);
    __syncthreads();
    zacc_i(acc);
    lstm_gemm_i8<0, 4>(X1, H10, ha, wb2, bq, acc);
    lstm_update_i8<1, true>(acc, cst2, bl2, dq2, 1.f, X0, QBUF, w, l16, grp, out0, b0, 31);
    __syncthreads();
  }

  // ---- quality L1: q_in = [h2_final(QBUF) | ctx(CTXB)], K=192, 16 tiles ----
#pragma unroll
  for (int it = 0; it < 2; ++it) {
    int tile = w + it * 8;             // 0..15: 2 M-tiles x 8 N-tiles (128 cols)
    int mt = tile & 1, nt = tile >> 1;
    int row = mt * 16 + l16;
    const u16* wl = wsb + OWQ1 + (size_t)(nt * 16 + l16) * 256 + grp * 8;
    f32x4 acc = (f32x4){0.f, 0.f, 0.f, 0.f};
#pragma unroll
    for (int kt = 0; kt < 4; ++kt) {
      s16x8 a = *(const s16x8*)(QBUF + row * 256 + (((kt * 4 + grp + row) & 15) << 4));
      s16x8 b = *(const s16x8*)(wl + kt * 32);
      acc = __builtin_amdgcn_mfma_f32_16x16x32_bf16(a, b, acc, 0, 0, 0);
    }
#pragma unroll
    for (int kc = 0; kc < 2; ++kc) {
      s16x8 a = *(const s16x8*)(CTXB + row * 128 + (((kc * 4 + grp + row) & 7) << 4));
      s16x8 b = *(const s16x8*)(wl + (4 + kc) * 32);
      acc = __builtin_amdgcn_mfma_f32_16x16x32_bf16(a, b, acc, 0, 0, 0);
    }
    int n = nt * 16 + l16;
    float bias = P.bq1[n];
#pragma unroll
    for (int r = 0; r < 4; ++r)
      lds_wr_bf16(QL1, 256, 15, mt * 16 + grp * 4 + r, n, fmaxf(acc[r] + bias, 0.f));
  }
  __syncthreads();

  // ---- quality L2: (32x128)@Wq2^T -> relu -> QL2 (stride 128) ----
  gemm_generic<128, 256, 15, 8>(QL1, wsb + OWQ2, w, l16, grp,
    [&](int, int mt, int nt, f32x4 a) {
      int n = nt * 16 + l16;
      float bias = P.bq2[n];
#pragma unroll
      for (int r = 0; r < 4; ++r)
        lds_wr_bf16(QL2, 128, 7, mt * 16 + grp * 4 + r, n, fmaxf(a[r] + bias, 0.f));
    });
  __syncthreads();

  if (tid < 256) {  // q3: per-row dot(64) + sigmoid
    int m = tid >> 3, k8 = (tid & 7) * 8;
    int slot = ((k8 >> 3) + m) & 7;
    s16x8 qv = *(const s16x8*)(QL2 + m * 128 + (slot << 4));
    float s = 0.f;
#pragma unroll
    for (int i = 0; i < 8; ++i) s += bf2f((u16)qv[i]) * P.Wq3[k8 + i];
    s += __shfl_xor(s, 1); s += __shfl_xor(s, 2); s += __shfl_xor(s, 4);
    if ((lane & 7) == 0) out1[b0 + m] = sigf(s + P.bq3[0]);
  }
}

// ---------------------------------------------------------------------------
extern "C" void kernel_launch(void* const* d_in, const int* in_sizes, int n_in,
                              void* d_out, int out_size, void* d_ws, size_t ws_size,
                              hipStream_t stream) {
  (void)in_sizes; (void)n_in; (void)out_size; (void)ws_size;
  KParams P;
  P.gc   = (const float*)d_in[0];
  // d_in[1] = sequence_length (always 32)
  P.W1   = (const float*)d_in[2];  P.b1   = (const float*)d_in[3];
  P.W2   = (const float*)d_in[4];  P.b2   = (const float*)d_in[5];
  P.W3   = (const float*)d_in[6];  P.b3   = (const float*)d_in[7];
  P.Wih1 = (const float*)d_in[8];  P.bih1 = (const float*)d_in[9];
  P.Whh1 = (const float*)d_in[10]; P.bhh1 = (const float*)d_in[11];
  P.Wih2 = (const float*)d_in[12]; P.bih2 = (const float*)d_in[13];
  P.Whh2 = (const float*)d_in[14]; P.bhh2 = (const float*)d_in[15];
  P.Wq1  = (const float*)d_in[16]; P.bq1  = (const float*)d_in[17];
  P.Wq2  = (const float*)d_in[18]; P.bq2  = (const float*)d_in[19];
  P.Wq3  = (const float*)d_in[20]; P.bq3  = (const float*)d_in[21];
  P.Wp1  = (const float*)d_in[22]; P.bp1  = (const float*)d_in[23];
  P.Wp2  = (const float*)d_in[24]; P.bp2  = (const float*)d_in[25];
  P.Wd1  = (const float*)d_in[26]; P.bd1  = (const float*)d_in[27];
  P.Wd2  = (const float*)d_in[28]; P.bd2  = (const float*)d_in[29];
  P.Wc1  = (const float*)d_in[30]; P.bc1  = (const float*)d_in[31];
  P.Wc2  = (const float*)d_in[32]; P.bc2  = (const float*)d_in[33];

  u16*   wsb     = (u16*)d_ws;
  char*  wsbytes = (char*)d_ws;
  float* wsf     = (float*)((char*)d_ws + OFP32_B);

  prep_bf16<<<483, 256, 0, stream>>>(P, wsb, wsf);
  prep_lstm_q<<<1024, 64, 0, stream>>>(P, wsbytes, wsf);
  planning_fused<<<512, 512, 0, stream>>>(P, wsb, wsbytes, wsf, (float*)d_out);
}

// Round 13
// 357.266 us; speedup vs baseline: 1.9661x; 1.9661x over previous
//
#include <hip/hip_runtime.h>
#include <cstdint>

// ---------------------------------------------------------------------------
// PlanningNetwork fused kernel for MI355X (gfx950).  B=16384,S=128,H=128,E=64,T=32.
// R13: R9 structure (64 rows/block, 256 blocks = 1/CU, i8 LSTM, 2 barriers/step)
//      + LAYER-1 weights staged ONCE into LDS (128KB, XOR-swizzled) -> layer-1
//      gemm has zero global loads; only layer-2 streams (128KB/step/CU).
//      LDS = 160KB: WL1[0,128K) + X/H panels [128K,160K). Encoder aliases into
//      WL1 region before staging; quality head aliases into it after t=31.
//      R12 lesson: fewer rows/block halves weight amortization -> never again.
// ---------------------------------------------------------------------------

typedef unsigned short u16;
typedef unsigned int   u32;
typedef float f32x4 __attribute__((ext_vector_type(4)));
typedef short s16x8 __attribute__((ext_vector_type(8)));
typedef int   i32x4 __attribute__((ext_vector_type(4)));

__device__ __forceinline__ u16 f2bf(float x) {
  u32 u = __float_as_uint(x);
  u32 r = u + 0x7fffu + ((u >> 16) & 1u);   // RNE
  return (u16)(r >> 16);
}
__device__ __forceinline__ float bf2f(u16 v) { return __uint_as_float(((u32)v) << 16); }
__device__ __forceinline__ float fexp2(float x) { return __builtin_amdgcn_exp2f(x); }
__device__ __forceinline__ float frcp(float x)  { return __builtin_amdgcn_rcpf(x); }
__device__ __forceinline__ float sigf(float x)  { return frcp(1.f + fexp2(-1.4426950408889634f * x)); }
__device__ __forceinline__ float tanh_(float x) { return 1.f - 2.f * frcp(1.f + fexp2(2.8853900817779268f * x)); }

struct KParams {
  const float* gc;
  const float *W1, *b1, *W2, *b2, *W3, *b3;
  const float *Wih1, *bih1, *Whh1, *bhh1;
  const float *Wih2, *bih2, *Whh2, *bhh2;
  const float *Wq1, *bq1, *Wq2, *bq2, *Wq3, *bq3;
  const float *Wp1, *bp1, *Wp2, *bp2;
  const float *Wd1, *bd1, *Wd2, *bd2;
  const float *Wc1, *bc1, *Wc2, *bc2;
};

// bf16 workspace element offsets (encoder/heads/quality only)
#define OW1   0
#define OW2   32768
#define OW3   65536
#define OWQ1  73728
#define OWQ2  106496
#define OWP1  114688
#define OWP2  116736
#define OWD1  117248
#define OWD2  119296
#define OWC1  119808
#define OWC2  121856
#define NBF16 122368
// byte offsets for i8 LSTM weights and fp32 scale/bias area
#define OWL1_B 245760
#define OWL2_B 376832
#define OFP32_B 507904   // fp32: bl1[512] bl2[512] dq1[512] dq2[512]

// ---------------------------------------------------------------------------
// Prep A: bf16 weights (encoder/heads/quality) + combined LSTM biases.
// ---------------------------------------------------------------------------
__global__ void prep_bf16(KParams P, u16* __restrict__ wsb, float* __restrict__ wsf) {
  int i = blockIdx.x * blockDim.x + threadIdx.x;
  int stride = gridDim.x * blockDim.x;
  for (; i < NBF16 + 1024; i += stride) {
    if (i < NBF16) {
      float v;
      int idx = i;
      if (idx < 32768) v = P.W1[idx];                                   // [256][128]
      else if ((idx -= 32768) < 32768) v = P.W2[idx];                   // [128][256]
      else if ((idx -= 32768) < 8192)  v = P.W3[idx];                   // [64][128]
      else if ((idx -= 8192) < 32768) {                                 // Wq1 padded to K=256
        int n = idx >> 8, k = idx & 255;
        v = (k < 192) ? P.Wq1[n * 192 + k] : 0.f;
      }
      else if ((idx -= 32768) < 8192) v = P.Wq2[idx];                   // [64][128]
      else if ((idx -= 8192) < 2048)  v = P.Wp1[idx];                   // [32][64]
      else if ((idx -= 2048) < 512) { int n = idx >> 5, k = idx & 31; v = (n < 8) ? P.Wp2[n * 32 + k] : 0.f; }
      else if ((idx -= 512) < 2048)  v = P.Wd1[idx];
      else if ((idx -= 2048) < 512) { int n = idx >> 5, k = idx & 31; v = (n < 1) ? P.Wd2[k] : 0.f; }
      else if ((idx -= 512) < 2048)  v = P.Wc1[idx];
      else { idx -= 2048; int n = idx >> 5, k = idx & 31; v = (n < 1) ? P.Wc2[k] : 0.f; }
      wsb[i] = f2bf(v);
    } else {
      int idx = i - NBF16;          // 0..1023 : combined permuted LSTM biases
      int l = idx >> 9, n = idx & 511;
      int gate = (n >> 4) & 3, j = ((n >> 6) << 4) | (n & 15);
      int orig = gate * 128 + j;
      wsf[idx] = (l == 0) ? (P.bih1[orig] + P.bhh1[orig]) : (P.bih2[orig] + P.bhh2[orig]);
    }
  }
}

// ---------------------------------------------------------------------------
// Prep B: LSTM i8 weights, one wave per output row (1024 rows).
// ---------------------------------------------------------------------------
__global__ void prep_lstm_q(KParams P, char* __restrict__ wsbytes, float* __restrict__ wsf) {
  int n = blockIdx.x;        // 0..1023
  int lane = threadIdx.x;    // 0..63
  int l = n >> 9, nn = n & 511;
  int gate = (nn >> 4) & 3, j = ((nn >> 6) << 4) | (nn & 15);
  int orig = gate * 128 + j;
  float v[4];
#pragma unroll
  for (int i = 0; i < 4; ++i) {
    int k = lane * 4 + i;
    if (l == 0) v[i] = (k < 128) ? P.Wih1[orig * 128 + k] : P.Whh1[orig * 128 + (k - 128)];
    else        v[i] = (k < 128) ? P.Whh2[orig * 128 + k] : P.Wih2[orig * 128 + (k - 128)];
  }
  float m = fmaxf(fmaxf(fabsf(v[0]), fabsf(v[1])), fmaxf(fabsf(v[2]), fabsf(v[3])));
  for (int off = 1; off < 64; off <<= 1) m = fmaxf(m, __shfl_xor(m, off));
  float inv = (m > 1e-30f) ? 127.f / m : 0.f;
  u32 pk = 0;
#pragma unroll
  for (int i = 0; i < 4; ++i) {
    int q = (int)rintf(v[i] * inv);
    q = max(-127, min(127, q));
    pk |= ((u32)(q & 255)) << (8 * i);
  }
  *(u32*)(wsbytes + (l ? OWL2_B : OWL1_B) + nn * 256 + lane * 4) = pk;
  if (lane == 0) wsf[1024 + l * 512 + nn] = (m > 1e-30f) ? (m * (1.f / (127.f * 127.f))) : 0.f;
}

// ---------------------------------------------------------------------------
// LDS write helper (bf16 panels) with per-row 16B-slot rotation.
// ---------------------------------------------------------------------------
__device__ __forceinline__ void lds_wr_bf16(char* sD, int stride, int mask, int m, int n, float v) {
  int slot = ((n >> 3) + m) & mask;
  *(u16*)(sD + m * stride + (slot << 4) + (n & 7) * 2) = f2bf(v);
}

// Generic LDS-A x global-B bf16 MFMA tile loop (64-row M, mt = tile&3).
template <int K, int STRIDE, int MASK, int NT, class EPI>
__device__ __forceinline__ void gemm_generic(const char* sA, const u16* W,
                                             int w, int l16, int grp, EPI epi) {
  constexpr int KT = K / 32;
  constexpr int ITMAX = (NT + 7) / 8;
#pragma unroll
  for (int it = 0; it < ITMAX; ++it) {
    int tile = w + it * 8;
    if (tile < NT) {
      int mt = tile & 3, nt = tile >> 2;
      int row = mt * 16 + l16;
      const u16* wl = W + (size_t)(nt * 16 + l16) * K + grp * 8;
      f32x4 acc = (f32x4){0.f, 0.f, 0.f, 0.f};
#pragma unroll
      for (int kt = 0; kt < KT; ++kt) {
        int slot = (kt * 4 + grp + row) & MASK;
        s16x8 a = *(const s16x8*)(sA + row * STRIDE + (slot << 4));
        s16x8 b = *(const s16x8*)(wl + kt * 32);
        acc = __builtin_amdgcn_mfma_f32_16x16x32_bf16(a, b, acc, 0, 0, 0);
      }
      epi(it, mt, nt, acc);
    }
  }
}

// ---------------------------------------------------------------------------
// LSTM i8 pieces. Half-panels [64 rows][128 i8] = [64][128B], 8 slots rot.
// ---------------------------------------------------------------------------
__device__ __forceinline__ void ldb4q(const char* const (&wb)[4], int kt, i32x4 (&bd)[4]) {
#pragma unroll
  for (int g = 0; g < 4; ++g) bd[g] = *(const i32x4*)(wb[g] + kt * 64);
}

__device__ __forceinline__ void zacc_i(i32x4 (&acc)[4][4]) {
#pragma unroll
  for (int a = 0; a < 4; ++a)
#pragma unroll
    for (int b = 0; b < 4; ++b) acc[a][b] = (i32x4){0, 0, 0, 0};
}

// Layer-2 (streaming weights from global, depth-2 prefetch), kt<2=X, kt>=2=H.
template <int KT0, int KT1>
__device__ __forceinline__ void lstm_gemm_i8(const char* X, const char* Hh,
                                             const int (&ha)[4][2],
                                             const char* const (&wb)[4],
                                             const i32x4 (&bpre)[4],
                                             i32x4 (&acc)[4][4]) {
  i32x4 bc[4], bn[4], ac[4], an[4];
#pragma unroll
  for (int g = 0; g < 4; ++g) bc[g] = bpre[g];
  {
    const char* base = (KT0 < 2) ? X : Hh;
#pragma unroll
    for (int mt = 0; mt < 4; ++mt) ac[mt] = *(const i32x4*)(base + ha[mt][KT0 & 1]);
  }
#pragma unroll
  for (int kt = KT0; kt < KT1; ++kt) {
    if (kt + 1 < KT1) {
      ldb4q(wb, kt + 1, bn);
      const char* base = (kt + 1 < 2) ? X : Hh;
#pragma unroll
      for (int mt = 0; mt < 4; ++mt) an[mt] = *(const i32x4*)(base + ha[mt][(kt + 1) & 1]);
    }
#pragma unroll
    for (int mt = 0; mt < 4; ++mt)
#pragma unroll
      for (int g = 0; g < 4; ++g)
        acc[mt][g] = __builtin_amdgcn_mfma_i32_16x16x64_i8(ac[mt], bc[g], acc[mt][g], 0, 0, 0);
    if (kt + 1 < KT1) {
#pragma unroll
      for (int g = 0; g < 4; ++g) bc[g] = bn[g];
#pragma unroll
      for (int mt = 0; mt < 4; ++mt) ac[mt] = an[mt];
    }
  }
}

// Layer-1 (weights LDS-resident, XOR-swizzled): zero global loads.
// wa[g][kt] = precomputed LDS byte offset of this thread's 16B B-fragment.
template <int KT0, int KT1>
__device__ __forceinline__ void lstm_gemm_l1(const char* X, const char* Hh,
                                             const int (&ha)[4][2],
                                             const char* wl1,
                                             const int (&wa)[4][4],
                                             i32x4 (&acc)[4][4]) {
#pragma unroll
  for (int kt = KT0; kt < KT1; ++kt) {
    const char* base = (kt < 2) ? X : Hh;
    i32x4 a[4], b[4];
#pragma unroll
    for (int g = 0; g < 4; ++g) b[g] = *(const i32x4*)(wl1 + wa[g][kt]);
#pragma unroll
    for (int mt = 0; mt < 4; ++mt) a[mt] = *(const i32x4*)(base + ha[mt][kt & 1]);
#pragma unroll
    for (int mt = 0; mt < 4; ++mt)
#pragma unroll
      for (int g = 0; g < 4; ++g)
        acc[mt][g] = __builtin_amdgcn_mfma_i32_16x16x64_i8(a[mt], b[g], acc[mt][g], 0, 0, 0);
  }
}

// Update: dequant + cell + write i8 h to dst panel (or bf16 to qbuf if FINAL).
// LAYER 1 also stores h2 to out0 (inline scalar NT — best measured config, R6).
template <int LAYER, bool FINAL>
__device__ __forceinline__ void lstm_update_i8(const i32x4 (&acc)[4][4], float (&cst)[4][4],
                                               const float (&bl)[4], const float (&dq)[4],
                                               float dqmul, char* dst, char* qbuf,
                                               int w, int l16, int grp,
                                               float* __restrict__ out0, int b0, int t) {
  const int j = w * 16 + l16;
  float dqe[4];
#pragma unroll
  for (int g = 0; g < 4; ++g) dqe[g] = dq[g] * dqmul;
#pragma unroll
  for (int mt = 0; mt < 4; ++mt) {
#pragma unroll
    for (int r = 0; r < 4; ++r) {
      const int m = mt * 16 + grp * 4 + r;
      float gi = (float)acc[mt][0][r] * dqe[0] + bl[0];
      float gf = (float)acc[mt][1][r] * dqe[1] + bl[1];
      float gg = (float)acc[mt][2][r] * dqe[2] + bl[2];
      float go = (float)acc[mt][3][r] * dqe[3] + bl[3];
      float c = sigf(gf) * cst[mt][r] + sigf(gi) * tanh_(gg);
      cst[mt][r] = c;
      float h = sigf(go) * tanh_(c);
      if (!FINAL) {
        int q = (int)rintf(h * 127.f);   // |h| < 1 strictly -> no clamp needed
        *(char*)(dst + m * 128 + ((((j >> 4) + m) & 7) << 4) + (j & 15)) = (char)q;
      } else {
        *(u16*)(qbuf + m * 256 + ((((j >> 3) + m) & 15) << 4) + (j & 7) * 2) = f2bf(h);
      }
      if (LAYER == 1)
        __builtin_nontemporal_store(h, &out0[(size_t)(b0 + m) * 4096 + (size_t)t * 128 + j]);
    }
  }
}

// ---------------------------------------------------------------------------
// Fused main kernel: 256 blocks x 512 threads, 64 batch rows per block.
// LDS (160KB):
//   WL1 region [0,128K): encoder bufs before staging; layer-1 i8 weights
//     (XOR-swizzled) during LSTM; QBUF/CTX2/QL1/QL2 after t=31.
//   Panels [128K,160K): X0,X1,H10,H11 (i8, 8KB each).
// ---------------------------------------------------------------------------
__global__ __launch_bounds__(512, 2) void planning_fused(KParams P,
                                                         const u16* __restrict__ wsb,
                                                         const char* __restrict__ wsbytes,
                                                         const float* __restrict__ wsf,
                                                         float* __restrict__ out) {
  __shared__ __align__(16) char smem[163840];
  // encoder-phase aliases (inside [0,128K))
  char* bufB = smem;              // 16KB gc staging [64][256B] rot-16
  char* bufA = smem + 16384;      // 32KB [64][512B] rot-32
  char* htmp = smem + 49152;      // 12KB 3 x [64][64B]
  char* CTXB = smem + 61440;      // 8KB [64][128B]
  // LSTM
  char* WL1  = smem;              // 128KB layer-1 weights (swizzled)
  char* X0   = smem + 131072;
  char* X1   = smem + 139264;
  char* H10  = smem + 147456;
  char* H11  = smem + 155648;
  // post-LSTM aliases (inside [0,128K), WL1 dead after t=31 L1 gemm)
  char* QBUF = smem;              // 16KB [64][256B] h2_final bf16
  char* CTX2 = smem + 16384;      // 8KB  [64][128B] ctx rebuilt from regs
  char* QL1  = smem + 32768;      // 16KB [64][256B]
  char* QL2  = smem + 49152;      // 8KB  [64][128B]

  const int tid = threadIdx.x;
  const int lane = tid & 63;
  const int w = tid >> 6;
  const int l16 = lane & 15;
  const int grp = lane >> 4;
  const int b0 = blockIdx.x * 64;

  float* out0 = out;                 // action_sequence (B,32,128)
  float* out1 = out + 67108864;      // plan_quality   (B,1)
  float* out2 = out + 67125248;      // plan_type      (B,8)
  float* out3 = out + 67256320;      // duration       (B,1)
  float* out4 = out + 67272704;      // cost           (B,1)
  float* out5 = out + 67289088;      // ctx            (B,64)

  // ---- stage goal_context -> bufB (bf16, rot-16) ----
#pragma unroll
  for (int ii = 0; ii < 4; ++ii) {
    int idx = tid + ii * 512;                 // 2048 = 64 rows * 32 float4
    int row = idx >> 5, c4 = idx & 31;
    f32x4 v = *(const f32x4*)(P.gc + (size_t)(b0 + row) * 128 + c4 * 4);
    u32 lo = (u32)f2bf(v[0]) | ((u32)f2bf(v[1]) << 16);
    u32 hi = (u32)f2bf(v[2]) | ((u32)f2bf(v[3]) << 16);
    int byte = row * 256 + ((((c4 >> 1) + row) & 15) << 4) + (c4 & 1) * 8;
    uint2 pk; pk.x = lo; pk.y = hi;
    *(uint2*)(bufB + byte) = pk;
  }
  __syncthreads();

  // ---- encoder L1: (64x128)@W1^T -> relu -> bufA (rot-32, stride 512) ----
  gemm_generic<128, 256, 15, 64>(bufB, wsb + OW1, w, l16, grp,
    [&](int, int mt, int nt, f32x4 a) {
      int n = nt * 16 + l16;
      float bias = P.b1[n];
#pragma unroll
      for (int r = 0; r < 4; ++r)
        lds_wr_bf16(bufA, 512, 31, mt * 16 + grp * 4 + r, n, fmaxf(a[r] + bias, 0.f));
    });
  __syncthreads();

  // ---- encoder L2: (64x256)@W2^T -> relu -> bufB ----
  gemm_generic<256, 512, 31, 32>(bufA, wsb + OW2, w, l16, grp,
    [&](int, int mt, int nt, f32x4 a) {
      int n = nt * 16 + l16;
      float bias = P.b2[n];
#pragma unroll
      for (int r = 0; r < 4; ++r)
        lds_wr_bf16(bufB, 256, 15, mt * 16 + grp * 4 + r, n, fmaxf(a[r] + bias, 0.f));
    });
  __syncthreads();

  // ---- zero X0 panel (x0 pad); ctx gemm bufB -> regs ----
  *(f32x4*)(X0 + tid * 16) = (f32x4){0.f, 0.f, 0.f, 0.f};   // 512*16B = 8KB
  f32x4 ctx3[2];
  gemm_generic<128, 256, 15, 16>(bufB, wsb + OW3, w, l16, grp,
    [&](int it, int, int, f32x4 a) { if (it == 0) ctx3[0] = a; else ctx3[1] = a; });
  __syncthreads();

  // ctx epilogue: +b3, -> out5, -> CTXB (bf16) + X0 (i8, scale 63.5); keep in regs
#pragma unroll
  for (int it = 0; it < 2; ++it) {
    int tile = w + it * 8;
    int mt = tile & 3, nt = tile >> 2;
    int n = nt * 16 + l16;
    float bias = P.b3[n];
#pragma unroll
    for (int r = 0; r < 4; ++r) {
      int m = mt * 16 + grp * 4 + r;
      float v = ctx3[it][r] + bias;
      ctx3[it][r] = v;                       // keep ctx in regs (rebuilt post-LSTM)
      out5[(size_t)(b0 + m) * 64 + n] = v;
      *(u16*)(CTXB + m * 128 + ((((n >> 3) + m) & 7) << 4) + (n & 7) * 2) = f2bf(v);
      int q = (int)rintf(v * 63.5f);
      q = max(-127, min(127, q));
      *(char*)(X0 + m * 128 + ((((n >> 4) + m) & 7) << 4) + (n & 15)) = (char)q;
    }
  }
  __syncthreads();

  // ---- heads level 1 (plan/dur/cost): relu(ctx@W^T+b) -> htmp ----
#pragma unroll
  for (int hh = 0; hh < 3; ++hh) {
    const u16* Wh = (hh == 0) ? (wsb + OWP1) : (hh == 1) ? (wsb + OWD1) : (wsb + OWC1);
    const float* bh = (hh == 0) ? P.bp1 : (hh == 1) ? P.bd1 : P.bc1;
    char* dsth = htmp + hh * 4096;
    gemm_generic<64, 128, 7, 8>(CTXB, Wh, w, l16, grp,
      [&](int, int mt, int nt, f32x4 a) {
        int n = nt * 16 + l16;
        float bias = bh[n];
#pragma unroll
        for (int r = 0; r < 4; ++r)
          lds_wr_bf16(dsth, 64, 3, mt * 16 + grp * 4 + r, n, fmaxf(a[r] + bias, 0.f));
      });
  }
  __syncthreads();

  // ---- heads level 2: plan softmax / duration / cost ----
#pragma unroll
  for (int it = 0; it < 2; ++it) {
    int tile = w + it * 8;
    if (tile < 12) {
      int head = tile >> 2, mt = tile & 3;
      int row = mt * 16 + l16;
      const char* aB = htmp + head * 4096;
      int slot = (grp + row) & 3;
      s16x8 a = *(const s16x8*)(aB + row * 64 + (slot << 4));
      const u16* W2h = (head == 0) ? (wsb + OWP2) : (head == 1) ? (wsb + OWD2) : (wsb + OWC2);
      s16x8 b = *(const s16x8*)(W2h + l16 * 32 + grp * 8);
      f32x4 acc = (f32x4){0.f, 0.f, 0.f, 0.f};
      acc = __builtin_amdgcn_mfma_f32_16x16x32_bf16(a, b, acc, 0, 0, 0);
      if (head == 0) {
        float bp = (l16 < 8) ? P.bp2[l16] : 0.f;
#pragma unroll
        for (int r = 0; r < 4; ++r) {
          int m = mt * 16 + grp * 4 + r;
          float v = (l16 < 8) ? (acc[r] + bp) : -3.0e38f;
          float mx = v;
          mx = fmaxf(mx, __shfl_xor(mx, 1));
          mx = fmaxf(mx, __shfl_xor(mx, 2));
          mx = fmaxf(mx, __shfl_xor(mx, 4));
          mx = fmaxf(mx, __shfl_xor(mx, 8));
          float e = (l16 < 8) ? fexp2(1.4426950408889634f * (v - mx)) : 0.f;
          float s = e;
          s += __shfl_xor(s, 1); s += __shfl_xor(s, 2);
          s += __shfl_xor(s, 4); s += __shfl_xor(s, 8);
          if (l16 < 8) out2[(size_t)(b0 + m) * 8 + l16] = e * frcp(s);
        }
      } else {
        float bb = (head == 1) ? P.bd2[0] : P.bc2[0];
        float* dst = (head == 1) ? out3 : out4;
        if (l16 == 0) {
#pragma unroll
          for (int r = 0; r < 4; ++r) {
            int m = mt * 16 + grp * 4 + r;
            dst[b0 + m] = fmaxf(acc[r] + bb, 0.f);
          }
        }
      }
    }
  }
  __syncthreads();   // encoder/head reads of [0,128K) done

  // ---- stage layer-1 weights global -> WL1 LDS (128KB, XOR-swizzled) ----
  // logical 16B chunk c: row n = c>>4, slot s = c&15; phys slot = s^(n&7).
#pragma unroll
  for (int it = 0; it < 16; ++it) {
    int c = tid + it * 512;                  // 0..8191
    int n = c >> 4, s = c & 15;
    f32x4 v = *(const f32x4*)(wsbytes + OWL1_B + (size_t)c * 16);
    *(f32x4*)(WL1 + n * 256 + ((s ^ (n & 7)) << 4)) = v;
  }
  __syncthreads();

  // ---- LSTM: 32 steps; L1 from LDS, L2 streamed; 2 barriers/step ----
  int ha[4][2];
#pragma unroll
  for (int mt = 0; mt < 4; ++mt) {
    int row = mt * 16 + l16;
#pragma unroll
    for (int k2 = 0; k2 < 2; ++k2)
      ha[mt][k2] = row * 128 + (((k2 * 4 + grp + row) & 7) << 4);
  }
  int wa[4][4];                   // LDS offsets of this thread's L1 B-fragments
#pragma unroll
  for (int g = 0; g < 4; ++g) {
    int n = w * 64 + g * 16 + l16;
#pragma unroll
    for (int kt = 0; kt < 4; ++kt)
      wa[g][kt] = n * 256 + ((((kt * 4 + grp)) ^ (l16 & 7)) << 4);
  }
  const char* wb2[4];
  float bl1[4], bl2[4], dq1[4], dq2[4];
#pragma unroll
  for (int g = 0; g < 4; ++g) {
    int nn = w * 64 + g * 16 + l16;
    wb2[g] = wsbytes + OWL2_B + (size_t)nn * 256 + grp * 16;
    bl1[g] = wsf[nn];          bl2[g] = wsf[512 + nn];
    dq1[g] = wsf[1024 + nn];   dq2[g] = wsf[1536 + nn];
  }
  float cst1[4][4], cst2[4][4];
#pragma unroll
  for (int a = 0; a < 4; ++a)
#pragma unroll
    for (int b = 0; b < 4; ++b) { cst1[a][b] = 0.f; cst2[a][b] = 0.f; }

  { // t = 0: layer1 reads only X half (ctx scale -> dqmul=2); layer2 only H half.
    i32x4 acc[4][4]; zacc_i(acc);
    lstm_gemm_l1<0, 2>(X0, H10, ha, WL1, wa, acc);
    i32x4 bq[4]; ldb4q(wb2, 2, bq);
    lstm_update_i8<0, false>(acc, cst1, bl1, dq1, 2.f, H11, QBUF, w, l16, grp, out0, b0, 0);
    __syncthreads();
    zacc_i(acc);
    lstm_gemm_i8<2, 4>(X0, H11, ha, wb2, bq, acc);
    lstm_update_i8<1, false>(acc, cst2, bl2, dq2, 1.f, X1, QBUF, w, l16, grp, out0, b0, 0);
    __syncthreads();
  }
  for (int t = 1; t < 31; ++t) {
    const char* Xr = (t & 1) ? X1 : X0;
    char*       Xw = (t & 1) ? X0 : X1;
    const char* Hr = (t & 1) ? H11 : H10;
    char*       Hw = (t & 1) ? H10 : H11;
    i32x4 acc[4][4]; zacc_i(acc);
    lstm_gemm_l1<0, 4>(Xr, Hr, ha, WL1, wa, acc);
    i32x4 bq[4]; ldb4q(wb2, 0, bq);
    lstm_update_i8<0, false>(acc, cst1, bl1, dq1, 1.f, Hw, QBUF, w, l16, grp, out0, b0, t);
    __syncthreads();
    zacc_i(acc);
    lstm_gemm_i8<0, 4>(Xr, Hw, ha, wb2, bq, acc);
    lstm_update_i8<1, false>(acc, cst2, bl2, dq2, 1.f, Xw, QBUF, w, l16, grp, out0, b0, t);
    __syncthreads();
  }
  { // t = 31 (odd): layer2 writes h2 as bf16 into QBUF (aliases WL1 - dead now).
    i32x4 acc[4][4]; zacc_i(acc);
    lstm_gemm_l1<0, 4>(X1, H11, ha, WL1, wa, acc);   // last WL1 use
    i32x4 bq[4]; ldb4q(wb2, 0, bq);
    lstm_update_i8<0, false>(acc, cst1, bl1, dq1, 1.f, H10, QBUF, w, l16, grp, out0, b0, 31);
    __syncthreads();                                 // all WL1 reads complete
    zacc_i(acc);
    lstm_gemm_i8<0, 4>(X1, H10, ha, wb2, bq, acc);
    lstm_update_i8<1, true>(acc, cst2, bl2, dq2, 1.f, X0, QBUF, w, l16, grp, out0, b0, 31);
    __syncthreads();
  }

  // ---- rebuild ctx (bf16) in CTX2 from registers ----
#pragma unroll
  for (int it = 0; it < 2; ++it) {
    int tile = w + it * 8;
    int mt = tile & 3, nt = tile >> 2;
    int n = nt * 16 + l16;
#pragma unroll
    for (int r = 0; r < 4; ++r) {
      int m = mt * 16 + grp * 4 + r;
      *(u16*)(CTX2 + m * 128 + ((((n >> 3) + m) & 7) << 4) + (n & 7) * 2) = f2bf(ctx3[it][r]);
    }
  }
  __syncthreads();

  // ---- quality L1: q_in = [h2_final(QBUF) | ctx(CTX2)], K=192 -> QL1 ----
  int hb[4][4];
#pragma unroll
  for (int mt = 0; mt < 4; ++mt) {
    int row = mt * 16 + l16;
#pragma unroll
    for (int k4 = 0; k4 < 4; ++k4)
      hb[mt][k4] = row * 256 + (((k4 * 4 + grp + row) & 15) << 4);
  }
#pragma unroll
  for (int it = 0; it < 4; ++it) {
    int tile = w + it * 8;
    int mt = tile & 3, nt = tile >> 2;
    int row = mt * 16 + l16;
    const u16* wl = wsb + OWQ1 + (size_t)(nt * 16 + l16) * 256 + grp * 8;
    f32x4 acc = (f32x4){0.f, 0.f, 0.f, 0.f};
#pragma unroll
    for (int kt = 0; kt < 4; ++kt) {
      s16x8 a = *(const s16x8*)(QBUF + hb[mt][kt]);
      s16x8 b = *(const s16x8*)(wl + kt * 32);
      acc = __builtin_amdgcn_mfma_f32_16x16x32_bf16(a, b, acc, 0, 0, 0);
    }
#pragma unroll
    for (int kc = 0; kc < 2; ++kc) {
      s16x8 a = *(const s16x8*)(CTX2 + row * 128 + (((kc * 4 + grp + row) & 7) << 4));
      s16x8 b = *(const s16x8*)(wl + (4 + kc) * 32);
      acc = __builtin_amdgcn_mfma_f32_16x16x32_bf16(a, b, acc, 0, 0, 0);
    }
    int n = nt * 16 + l16;
    float bias = P.bq1[n];
#pragma unroll
    for (int r = 0; r < 4; ++r)
      lds_wr_bf16(QL1, 256, 15, mt * 16 + grp * 4 + r, n, fmaxf(acc[r] + bias, 0.f));
  }
  __syncthreads();

  // ---- quality L2: (64x128)@Wq2^T -> relu -> QL2 (stride 128) ----
  gemm_generic<128, 256, 15, 16>(QL1, wsb + OWQ2, w, l16, grp,
    [&](int, int mt, int nt, f32x4 a) {
      int n = nt * 16 + l16;
      float bias = P.bq2[n];
#pragma unroll
      for (int r = 0; r < 4; ++r)
        lds_wr_bf16(QL2, 128, 7, mt * 16 + grp * 4 + r, n, fmaxf(a[r] + bias, 0.f));
    });
  __syncthreads();

  {  // q3: per-row dot(64) + sigmoid
    int m = tid >> 3, k8 = (tid & 7) * 8;
    int slot = ((k8 >> 3) + m) & 7;
    s16x8 qv = *(const s16x8*)(QL2 + m * 128 + (slot << 4));
    float s = 0.f;
#pragma unroll
    for (int i = 0; i < 8; ++i) s += bf2f((u16)qv[i]) * P.Wq3[k8 + i];
    s += __shfl_xor(s, 1); s += __shfl_xor(s, 2); s += __shfl_xor(s, 4);
    if ((lane & 7) == 0) out1[b0 + m] = sigf(s + P.bq3[0]);
  }
}

// ---------------------------------------------------------------------------
extern "C" void kernel_launch(void* const* d_in, const int* in_sizes, int n_in,
                              void* d_out, int out_size, void* d_ws, size_t ws_size,
                              hipStream_t stream) {
  (void)in_sizes; (void)n_in; (void)out_size; (void)ws_size;
  KParams P;
  P.gc   = (const float*)d_in[0];
  // d_in[1] = sequence_length (always 32)
  P.W1   = (const float*)d_in[2];  P.b1   = (const float*)d_in[3];
  P.W2   = (const float*)d_in[4];  P.b2   = (const float*)d_in[5];
  P.W3   = (const float*)d_in[6];  P.b3   = (const float*)d_in[7];
  P.Wih1 = (const float*)d_in[8];  P.bih1 = (const float*)d_in[9];
  P.Whh1 = (const float*)d_in[10]; P.bhh1 = (const float*)d_in[11];
  P.Wih2 = (const float*)d_in[12]; P.bih2 = (const float*)d_in[13];
  P.Whh2 = (const float*)d_in[14]; P.bhh2 = (const float*)d_in[15];
  P.Wq1  = (const float*)d_in[16]; P.bq1  = (const float*)d_in[17];
  P.Wq2  = (const float*)d_in[18]; P.bq2  = (const float*)d_in[19];
  P.Wq3  = (const float*)d_in[20]; P.bq3  = (const float*)d_in[21];
  P.Wp1  = (const float*)d_in[22]; P.bp1  = (const float*)d_in[23];
  P.Wp2  = (const float*)d_in[24]; P.bp2  = (const float*)d_in[25];
  P.Wd1  = (const float*)d_in[26]; P.bd1  = (const float*)d_in[27];
  P.Wd2  = (const float*)d_in[28]; P.bd2  = (const float*)d_in[29];
  P.Wc1  = (const float*)d_in[30]; P.bc1  = (const float*)d_in[31];
  P.Wc2  = (const float*)d_in[32]; P.bc2  = (const float*)d_in[33];

  u16*   wsb     = (u16*)d_ws;
  char*  wsbytes = (char*)d_ws;
  float* wsf     = (float*)((char*)d_ws + OFP32_B);

  prep_bf16<<<483, 256, 0, stream>>>(P, wsb, wsf);
  prep_lstm_q<<<1024, 64, 0, stream>>>(P, wsbytes, wsf);
  planning_fused<<<256, 512, 0, stream>>>(P, wsb, wsbytes, wsf, (float*)d_out);
}

// Round 14
// 312.521 us; speedup vs baseline: 2.2476x; 1.1432x over previous
//
#include <hip/hip_runtime.h>
#include <cstdint>

// ---------------------------------------------------------------------------
// PlanningNetwork fused kernel for MI355X (gfx950).  B=16384,S=128,H=128,E=64,T=32.
// R14: R13 + (a) WL1 swizzle XORs full l16 (n&15) -> 8-way bank conflict
//      becomes 4-way (R13 counter: 4.7M conflicts); (b) cell update refactored
//      from 10 to 7 transcendentals (tanh = (1-e^-2x)/(1+e^-2x), single rcp of
//      merged denominators; exp2 args folded into dequant FMA).
// ---------------------------------------------------------------------------

typedef unsigned short u16;
typedef unsigned int   u32;
typedef float f32x4 __attribute__((ext_vector_type(4)));
typedef short s16x8 __attribute__((ext_vector_type(8)));
typedef int   i32x4 __attribute__((ext_vector_type(4)));

__device__ __forceinline__ u16 f2bf(float x) {
  u32 u = __float_as_uint(x);
  u32 r = u + 0x7fffu + ((u >> 16) & 1u);   // RNE
  return (u16)(r >> 16);
}
__device__ __forceinline__ float bf2f(u16 v) { return __uint_as_float(((u32)v) << 16); }
__device__ __forceinline__ float fexp2(float x) { return __builtin_amdgcn_exp2f(x); }
__device__ __forceinline__ float frcp(float x)  { return __builtin_amdgcn_rcpf(x); }
__device__ __forceinline__ float sigf(float x)  { return frcp(1.f + fexp2(-1.4426950408889634f * x)); }

struct KParams {
  const float* gc;
  const float *W1, *b1, *W2, *b2, *W3, *b3;
  const float *Wih1, *bih1, *Whh1, *bhh1;
  const float *Wih2, *bih2, *Whh2, *bhh2;
  const float *Wq1, *bq1, *Wq2, *bq2, *Wq3, *bq3;
  const float *Wp1, *bp1, *Wp2, *bp2;
  const float *Wd1, *bd1, *Wd2, *bd2;
  const float *Wc1, *bc1, *Wc2, *bc2;
};

// bf16 workspace element offsets (encoder/heads/quality only)
#define OW1   0
#define OW2   32768
#define OW3   65536
#define OWQ1  73728
#define OWQ2  106496
#define OWP1  114688
#define OWP2  116736
#define OWD1  117248
#define OWD2  119296
#define OWC1  119808
#define OWC2  121856
#define NBF16 122368
// byte offsets for i8 LSTM weights and fp32 scale/bias area
#define OWL1_B 245760
#define OWL2_B 376832
#define OFP32_B 507904   // fp32: bl1[512] bl2[512] dq1[512] dq2[512]

// ---------------------------------------------------------------------------
// Prep A: bf16 weights (encoder/heads/quality) + combined LSTM biases.
// ---------------------------------------------------------------------------
__global__ void prep_bf16(KParams P, u16* __restrict__ wsb, float* __restrict__ wsf) {
  int i = blockIdx.x * blockDim.x + threadIdx.x;
  int stride = gridDim.x * blockDim.x;
  for (; i < NBF16 + 1024; i += stride) {
    if (i < NBF16) {
      float v;
      int idx = i;
      if (idx < 32768) v = P.W1[idx];                                   // [256][128]
      else if ((idx -= 32768) < 32768) v = P.W2[idx];                   // [128][256]
      else if ((idx -= 32768) < 8192)  v = P.W3[idx];                   // [64][128]
      else if ((idx -= 8192) < 32768) {                                 // Wq1 padded to K=256
        int n = idx >> 8, k = idx & 255;
        v = (k < 192) ? P.Wq1[n * 192 + k] : 0.f;
      }
      else if ((idx -= 32768) < 8192) v = P.Wq2[idx];                   // [64][128]
      else if ((idx -= 8192) < 2048)  v = P.Wp1[idx];                   // [32][64]
      else if ((idx -= 2048) < 512) { int n = idx >> 5, k = idx & 31; v = (n < 8) ? P.Wp2[n * 32 + k] : 0.f; }
      else if ((idx -= 512) < 2048)  v = P.Wd1[idx];
      else if ((idx -= 2048) < 512) { int n = idx >> 5, k = idx & 31; v = (n < 1) ? P.Wd2[k] : 0.f; }
      else if ((idx -= 512) < 2048)  v = P.Wc1[idx];
      else { idx -= 2048; int n = idx >> 5, k = idx & 31; v = (n < 1) ? P.Wc2[k] : 0.f; }
      wsb[i] = f2bf(v);
    } else {
      int idx = i - NBF16;          // 0..1023 : combined permuted LSTM biases
      int l = idx >> 9, n = idx & 511;
      int gate = (n >> 4) & 3, j = ((n >> 6) << 4) | (n & 15);
      int orig = gate * 128 + j;
      wsf[idx] = (l == 0) ? (P.bih1[orig] + P.bhh1[orig]) : (P.bih2[orig] + P.bhh2[orig]);
    }
  }
}

// ---------------------------------------------------------------------------
// Prep B: LSTM i8 weights, one wave per output row (1024 rows).
// ---------------------------------------------------------------------------
__global__ void prep_lstm_q(KParams P, char* __restrict__ wsbytes, float* __restrict__ wsf) {
  int n = blockIdx.x;        // 0..1023
  int lane = threadIdx.x;    // 0..63
  int l = n >> 9, nn = n & 511;
  int gate = (nn >> 4) & 3, j = ((nn >> 6) << 4) | (nn & 15);
  int orig = gate * 128 + j;
  float v[4];
#pragma unroll
  for (int i = 0; i < 4; ++i) {
    int k = lane * 4 + i;
    if (l == 0) v[i] = (k < 128) ? P.Wih1[orig * 128 + k] : P.Whh1[orig * 128 + (k - 128)];
    else        v[i] = (k < 128) ? P.Whh2[orig * 128 + k] : P.Wih2[orig * 128 + (k - 128)];
  }
  float m = fmaxf(fmaxf(fabsf(v[0]), fabsf(v[1])), fmaxf(fabsf(v[2]), fabsf(v[3])));
  for (int off = 1; off < 64; off <<= 1) m = fmaxf(m, __shfl_xor(m, off));
  float inv = (m > 1e-30f) ? 127.f / m : 0.f;
  u32 pk = 0;
#pragma unroll
  for (int i = 0; i < 4; ++i) {
    int q = (int)rintf(v[i] * inv);
    q = max(-127, min(127, q));
    pk |= ((u32)(q & 255)) << (8 * i);
  }
  *(u32*)(wsbytes + (l ? OWL2_B : OWL1_B) + nn * 256 + lane * 4) = pk;
  if (lane == 0) wsf[1024 + l * 512 + nn] = (m > 1e-30f) ? (m * (1.f / (127.f * 127.f))) : 0.f;
}

// ---------------------------------------------------------------------------
// LDS write helper (bf16 panels) with per-row 16B-slot rotation.
// ---------------------------------------------------------------------------
__device__ __forceinline__ void lds_wr_bf16(char* sD, int stride, int mask, int m, int n, float v) {
  int slot = ((n >> 3) + m) & mask;
  *(u16*)(sD + m * stride + (slot << 4) + (n & 7) * 2) = f2bf(v);
}

// Generic LDS-A x global-B bf16 MFMA tile loop (64-row M, mt = tile&3).
template <int K, int STRIDE, int MASK, int NT, class EPI>
__device__ __forceinline__ void gemm_generic(const char* sA, const u16* W,
                                             int w, int l16, int grp, EPI epi) {
  constexpr int KT = K / 32;
  constexpr int ITMAX = (NT + 7) / 8;
#pragma unroll
  for (int it = 0; it < ITMAX; ++it) {
    int tile = w + it * 8;
    if (tile < NT) {
      int mt = tile & 3, nt = tile >> 2;
      int row = mt * 16 + l16;
      const u16* wl = W + (size_t)(nt * 16 + l16) * K + grp * 8;
      f32x4 acc = (f32x4){0.f, 0.f, 0.f, 0.f};
#pragma unroll
      for (int kt = 0; kt < KT; ++kt) {
        int slot = (kt * 4 + grp + row) & MASK;
        s16x8 a = *(const s16x8*)(sA + row * STRIDE + (slot << 4));
        s16x8 b = *(const s16x8*)(wl + kt * 32);
        acc = __builtin_amdgcn_mfma_f32_16x16x32_bf16(a, b, acc, 0, 0, 0);
      }
      epi(it, mt, nt, acc);
    }
  }
}

// ---------------------------------------------------------------------------
// LSTM i8 pieces. Half-panels [64 rows][128 i8] = [64][128B], 8 slots rot.
// ---------------------------------------------------------------------------
__device__ __forceinline__ void ldb4q(const char* const (&wb)[4], int kt, i32x4 (&bd)[4]) {
#pragma unroll
  for (int g = 0; g < 4; ++g) bd[g] = *(const i32x4*)(wb[g] + kt * 64);
}

__device__ __forceinline__ void zacc_i(i32x4 (&acc)[4][4]) {
#pragma unroll
  for (int a = 0; a < 4; ++a)
#pragma unroll
    for (int b = 0; b < 4; ++b) acc[a][b] = (i32x4){0, 0, 0, 0};
}

// Layer-2 (streaming weights from global, depth-2 prefetch), kt<2=X, kt>=2=H.
template <int KT0, int KT1>
__device__ __forceinline__ void lstm_gemm_i8(const char* X, const char* Hh,
                                             const int (&ha)[4][2],
                                             const char* const (&wb)[4],
                                             const i32x4 (&bpre)[4],
                                             i32x4 (&acc)[4][4]) {
  i32x4 bc[4], bn[4], ac[4], an[4];
#pragma unroll
  for (int g = 0; g < 4; ++g) bc[g] = bpre[g];
  {
    const char* base = (KT0 < 2) ? X : Hh;
#pragma unroll
    for (int mt = 0; mt < 4; ++mt) ac[mt] = *(const i32x4*)(base + ha[mt][KT0 & 1]);
  }
#pragma unroll
  for (int kt = KT0; kt < KT1; ++kt) {
    if (kt + 1 < KT1) {
      ldb4q(wb, kt + 1, bn);
      const char* base = (kt + 1 < 2) ? X : Hh;
#pragma unroll
      for (int mt = 0; mt < 4; ++mt) an[mt] = *(const i32x4*)(base + ha[mt][(kt + 1) & 1]);
    }
#pragma unroll
    for (int mt = 0; mt < 4; ++mt)
#pragma unroll
      for (int g = 0; g < 4; ++g)
        acc[mt][g] = __builtin_amdgcn_mfma_i32_16x16x64_i8(ac[mt], bc[g], acc[mt][g], 0, 0, 0);
    if (kt + 1 < KT1) {
#pragma unroll
      for (int g = 0; g < 4; ++g) bc[g] = bn[g];
#pragma unroll
      for (int mt = 0; mt < 4; ++mt) ac[mt] = an[mt];
    }
  }
}

// Layer-1 (weights LDS-resident, XOR-swizzled with full l16): zero global loads.
template <int KT0, int KT1>
__device__ __forceinline__ void lstm_gemm_l1(const char* X, const char* Hh,
                                             const int (&ha)[4][2],
                                             const char* wl1,
                                             const int (&wa)[4][4],
                                             i32x4 (&acc)[4][4]) {
#pragma unroll
  for (int kt = KT0; kt < KT1; ++kt) {
    const char* base = (kt < 2) ? X : Hh;
    i32x4 a[4], b[4];
#pragma unroll
    for (int g = 0; g < 4; ++g) b[g] = *(const i32x4*)(wl1 + wa[g][kt]);
#pragma unroll
    for (int mt = 0; mt < 4; ++mt) a[mt] = *(const i32x4*)(base + ha[mt][kt & 1]);
#pragma unroll
    for (int mt = 0; mt < 4; ++mt)
#pragma unroll
      for (int g = 0; g < 4; ++g)
        acc[mt][g] = __builtin_amdgcn_mfma_i32_16x16x64_i8(a[mt], b[g], acc[mt][g], 0, 0, 0);
  }
}

// Update: dequant + cell + write i8 h to dst panel (or bf16 to qbuf if FINAL).
// 7-transcendental formulation (5 exp2 + 2 rcp), algebraically identical:
//   sig(x) = 1/(1+e^-x); tanh(x) = (1-e^-2x)/(1+e^-2x)
//   c = [c'*(1+ei)(1+eg) + (1-eg)(1+ef)] / [(1+ef)(1+ei)(1+eg)]
//   h = (1-ec) / [(1+eo)(1+ec)]
// exp2 args folded into dequant FMA via precomputed -K*dq / -K*bl.
template <int LAYER, bool FINAL>
__device__ __forceinline__ void lstm_update_i8(const i32x4 (&acc)[4][4], float (&cst)[4][4],
                                               const float (&bl)[4], const float (&dq)[4],
                                               float dqmul, char* dst, char* qbuf,
                                               int w, int l16, int grp,
                                               float* __restrict__ out0, int b0, int t) {
  const int j = w * 16 + l16;
  const float K1 = 1.4426950408889634f;   // log2(e)
  const float K2 = 2.8853900817779268f;   // 2*log2(e)
  float kdq[4], kbl[4];
  kdq[0] = -K1 * dq[0] * dqmul; kbl[0] = -K1 * bl[0];   // i
  kdq[1] = -K1 * dq[1] * dqmul; kbl[1] = -K1 * bl[1];   // f
  kdq[2] = -K2 * dq[2] * dqmul; kbl[2] = -K2 * bl[2];   // g (double angle)
  kdq[3] = -K1 * dq[3] * dqmul; kbl[3] = -K1 * bl[3];   // o
#pragma unroll
  for (int mt = 0; mt < 4; ++mt) {
#pragma unroll
    for (int r = 0; r < 4; ++r) {
      const int m = mt * 16 + grp * 4 + r;
      float ei = fexp2(fmaf((float)acc[mt][0][r], kdq[0], kbl[0]));  // e^-gi
      float ef = fexp2(fmaf((float)acc[mt][1][r], kdq[1], kbl[1]));  // e^-gf
      float eg = fexp2(fmaf((float)acc[mt][2][r], kdq[2], kbl[2]));  // e^-2gg
      float eo = fexp2(fmaf((float)acc[mt][3][r], kdq[3], kbl[3]));  // e^-go
      float D1 = 1.f + ef;
      float D2 = fmaf(ei, eg, 1.f + ei + eg);            // (1+ei)(1+eg)
      float num = fmaf(cst[mt][r], D2, (1.f - eg) * D1);
      float c = num * frcp(D1 * D2);
      cst[mt][r] = c;
      float ec = fexp2(c * -K2);                          // e^-2c
      float h = (1.f - ec) * frcp((1.f + eo) * (1.f + ec));
      if (!FINAL) {
        int q = (int)rintf(h * 127.f);   // |h| < 1 strictly -> no clamp needed
        *(char*)(dst + m * 128 + ((((j >> 4) + m) & 7) << 4) + (j & 15)) = (char)q;
      } else {
        *(u16*)(qbuf + m * 256 + ((((j >> 3) + m) & 15) << 4) + (j & 7) * 2) = f2bf(h);
      }
      if (LAYER == 1)
        __builtin_nontemporal_store(h, &out0[(size_t)(b0 + m) * 4096 + (size_t)t * 128 + j]);
    }
  }
}

// ---------------------------------------------------------------------------
// Fused main kernel: 256 blocks x 512 threads, 64 batch rows per block.
// LDS (160KB):
//   WL1 region [0,128K): encoder bufs before staging; layer-1 i8 weights
//     (XOR-l16 swizzled) during LSTM; QBUF/CTX2/QL1/QL2 after t=31.
//   Panels [128K,160K): X0,X1,H10,H11 (i8, 8KB each).
// ---------------------------------------------------------------------------
__global__ __launch_bounds__(512, 2) void planning_fused(KParams P,
                                                         const u16* __restrict__ wsb,
                                                         const char* __restrict__ wsbytes,
                                                         const float* __restrict__ wsf,
                                                         float* __restrict__ out) {
  __shared__ __align__(16) char smem[163840];
  // encoder-phase aliases (inside [0,128K))
  char* bufB = smem;              // 16KB gc staging [64][256B] rot-16
  char* bufA = smem + 16384;      // 32KB [64][512B] rot-32
  char* htmp = smem + 49152;      // 12KB 3 x [64][64B]
  char* CTXB = smem + 61440;      // 8KB [64][128B]
  // LSTM
  char* WL1  = smem;              // 128KB layer-1 weights (swizzled)
  char* X0   = smem + 131072;
  char* X1   = smem + 139264;
  char* H10  = smem + 147456;
  char* H11  = smem + 155648;
  // post-LSTM aliases (inside [0,128K), WL1 dead after t=31 L1 gemm)
  char* QBUF = smem;              // 16KB [64][256B] h2_final bf16
  char* CTX2 = smem + 16384;      // 8KB  [64][128B] ctx rebuilt from regs
  char* QL1  = smem + 32768;      // 16KB [64][256B]
  char* QL2  = smem + 49152;      // 8KB  [64][128B]

  const int tid = threadIdx.x;
  const int lane = tid & 63;
  const int w = tid >> 6;
  const int l16 = lane & 15;
  const int grp = lane >> 4;
  const int b0 = blockIdx.x * 64;

  float* out0 = out;                 // action_sequence (B,32,128)
  float* out1 = out + 67108864;      // plan_quality   (B,1)
  float* out2 = out + 67125248;      // plan_type      (B,8)
  float* out3 = out + 67256320;      // duration       (B,1)
  float* out4 = out + 67272704;      // cost           (B,1)
  float* out5 = out + 67289088;      // ctx            (B,64)

  // ---- stage goal_context -> bufB (bf16, rot-16) ----
#pragma unroll
  for (int ii = 0; ii < 4; ++ii) {
    int idx = tid + ii * 512;                 // 2048 = 64 rows * 32 float4
    int row = idx >> 5, c4 = idx & 31;
    f32x4 v = *(const f32x4*)(P.gc + (size_t)(b0 + row) * 128 + c4 * 4);
    u32 lo = (u32)f2bf(v[0]) | ((u32)f2bf(v[1]) << 16);
    u32 hi = (u32)f2bf(v[2]) | ((u32)f2bf(v[3]) << 16);
    int byte = row * 256 + ((((c4 >> 1) + row) & 15) << 4) + (c4 & 1) * 8;
    uint2 pk; pk.x = lo; pk.y = hi;
    *(uint2*)(bufB + byte) = pk;
  }
  __syncthreads();

  // ---- encoder L1: (64x128)@W1^T -> relu -> bufA (rot-32, stride 512) ----
  gemm_generic<128, 256, 15, 64>(bufB, wsb + OW1, w, l16, grp,
    [&](int, int mt, int nt, f32x4 a) {
      int n = nt * 16 + l16;
      float bias = P.b1[n];
#pragma unroll
      for (int r = 0; r < 4; ++r)
        lds_wr_bf16(bufA, 512, 31, mt * 16 + grp * 4 + r, n, fmaxf(a[r] + bias, 0.f));
    });
  __syncthreads();

  // ---- encoder L2: (64x256)@W2^T -> relu -> bufB ----
  gemm_generic<256, 512, 31, 32>(bufA, wsb + OW2, w, l16, grp,
    [&](int, int mt, int nt, f32x4 a) {
      int n = nt * 16 + l16;
      float bias = P.b2[n];
#pragma unroll
      for (int r = 0; r < 4; ++r)
        lds_wr_bf16(bufB, 256, 15, mt * 16 + grp * 4 + r, n, fmaxf(a[r] + bias, 0.f));
    });
  __syncthreads();

  // ---- zero X0 panel (x0 pad); ctx gemm bufB -> regs ----
  *(f32x4*)(X0 + tid * 16) = (f32x4){0.f, 0.f, 0.f, 0.f};   // 512*16B = 8KB
  f32x4 ctx3[2];
  gemm_generic<128, 256, 15, 16>(bufB, wsb + OW3, w, l16, grp,
    [&](int it, int, int, f32x4 a) { if (it == 0) ctx3[0] = a; else ctx3[1] = a; });
  __syncthreads();

  // ctx epilogue: +b3, -> out5, -> CTXB (bf16) + X0 (i8, scale 63.5); keep in regs
#pragma unroll
  for (int it = 0; it < 2; ++it) {
    int tile = w + it * 8;
    int mt = tile & 3, nt = tile >> 2;
    int n = nt * 16 + l16;
    float bias = P.b3[n];
#pragma unroll
    for (int r = 0; r < 4; ++r) {
      int m = mt * 16 + grp * 4 + r;
      float v = ctx3[it][r] + bias;
      ctx3[it][r] = v;                       // keep ctx in regs (rebuilt post-LSTM)
      out5[(size_t)(b0 + m) * 64 + n] = v;
      *(u16*)(CTXB + m * 128 + ((((n >> 3) + m) & 7) << 4) + (n & 7) * 2) = f2bf(v);
      int q = (int)rintf(v * 63.5f);
      q = max(-127, min(127, q));
      *(char*)(X0 + m * 128 + ((((n >> 4) + m) & 7) << 4) + (n & 15)) = (char)q;
    }
  }
  __syncthreads();

  // ---- heads level 1 (plan/dur/cost): relu(ctx@W^T+b) -> htmp ----
#pragma unroll
  for (int hh = 0; hh < 3; ++hh) {
    const u16* Wh = (hh == 0) ? (wsb + OWP1) : (hh == 1) ? (wsb + OWD1) : (wsb + OWC1);
    const float* bh = (hh == 0) ? P.bp1 : (hh == 1) ? P.bd1 : P.bc1;
    char* dsth = htmp + hh * 4096;
    gemm_generic<64, 128, 7, 8>(CTXB, Wh, w, l16, grp,
      [&](int, int mt, int nt, f32x4 a) {
        int n = nt * 16 + l16;
        float bias = bh[n];
#pragma unroll
        for (int r = 0; r < 4; ++r)
          lds_wr_bf16(dsth, 64, 3, mt * 16 + grp * 4 + r, n, fmaxf(a[r] + bias, 0.f));
      });
  }
  __syncthreads();

  // ---- heads level 2: plan softmax / duration / cost ----
#pragma unroll
  for (int it = 0; it < 2; ++it) {
    int tile = w + it * 8;
    if (tile < 12) {
      int head = tile >> 2, mt = tile & 3;
      int row = mt * 16 + l16;
      const char* aB = htmp + head * 4096;
      int slot = (grp + row) & 3;
      s16x8 a = *(const s16x8*)(aB + row * 64 + (slot << 4));
      const u16* W2h = (head == 0) ? (wsb + OWP2) : (head == 1) ? (wsb + OWD2) : (wsb + OWC2);
      s16x8 b = *(const s16x8*)(W2h + l16 * 32 + grp * 8);
      f32x4 acc = (f32x4){0.f, 0.f, 0.f, 0.f};
      acc = __builtin_amdgcn_mfma_f32_16x16x32_bf16(a, b, acc, 0, 0, 0);
      if (head == 0) {
        float bp = (l16 < 8) ? P.bp2[l16] : 0.f;
#pragma unroll
        for (int r = 0; r < 4; ++r) {
          int m = mt * 16 + grp * 4 + r;
          float v = (l16 < 8) ? (acc[r] + bp) : -3.0e38f;
          float mx = v;
          mx = fmaxf(mx, __shfl_xor(mx, 1));
          mx = fmaxf(mx, __shfl_xor(mx, 2));
          mx = fmaxf(mx, __shfl_xor(mx, 4));
          mx = fmaxf(mx, __shfl_xor(mx, 8));
          float e = (l16 < 8) ? fexp2(1.4426950408889634f * (v - mx)) : 0.f;
          float s = e;
          s += __shfl_xor(s, 1); s += __shfl_xor(s, 2);
          s += __shfl_xor(s, 4); s += __shfl_xor(s, 8);
          if (l16 < 8) out2[(size_t)(b0 + m) * 8 + l16] = e * frcp(s);
        }
      } else {
        float bb = (head == 1) ? P.bd2[0] : P.bc2[0];
        float* dst = (head == 1) ? out3 : out4;
        if (l16 == 0) {
#pragma unroll
          for (int r = 0; r < 4; ++r) {
            int m = mt * 16 + grp * 4 + r;
            dst[b0 + m] = fmaxf(acc[r] + bb, 0.f);
          }
        }
      }
    }
  }
  __syncthreads();   // encoder/head reads of [0,128K) done

  // ---- stage layer-1 weights global -> WL1 LDS (128KB, XOR-l16 swizzled) ----
  // logical 16B chunk c: row n = c>>4, slot s = c&15; phys slot = s^(n&15).
#pragma unroll
  for (int it = 0; it < 16; ++it) {
    int c = tid + it * 512;                  // 0..8191
    int n = c >> 4, s = c & 15;
    f32x4 v = *(const f32x4*)(wsbytes + OWL1_B + (size_t)c * 16);
    *(f32x4*)(WL1 + n * 256 + ((s ^ (n & 15)) << 4)) = v;
  }
  __syncthreads();

  // ---- LSTM: 32 steps; L1 from LDS, L2 streamed; 2 barriers/step ----
  int ha[4][2];
#pragma unroll
  for (int mt = 0; mt < 4; ++mt) {
    int row = mt * 16 + l16;
#pragma unroll
    for (int k2 = 0; k2 < 2; ++k2)
      ha[mt][k2] = row * 128 + (((k2 * 4 + grp + row) & 7) << 4);
  }
  int wa[4][4];                   // LDS offsets of this thread's L1 B-fragments
#pragma unroll
  for (int g = 0; g < 4; ++g) {
    int n = w * 64 + g * 16 + l16;
#pragma unroll
    for (int kt = 0; kt < 4; ++kt)
      wa[g][kt] = n * 256 + (((kt * 4 + grp) ^ l16) << 4);   // n&15 == l16
  }
  const char* wb2[4];
  float bl1[4], bl2[4], dq1[4], dq2[4];
#pragma unroll
  for (int g = 0; g < 4; ++g) {
    int nn = w * 64 + g * 16 + l16;
    wb2[g] = wsbytes + OWL2_B + (size_t)nn * 256 + grp * 16;
    bl1[g] = wsf[nn];          bl2[g] = wsf[512 + nn];
    dq1[g] = wsf[1024 + nn];   dq2[g] = wsf[1536 + nn];
  }
  float cst1[4][4], cst2[4][4];
#pragma unroll
  for (int a = 0; a < 4; ++a)
#pragma unroll
    for (int b = 0; b < 4; ++b) { cst1[a][b] = 0.f; cst2[a][b] = 0.f; }

  { // t = 0: layer1 reads only X half (ctx scale -> dqmul=2); layer2 only H half.
    i32x4 acc[4][4]; zacc_i(acc);
    lstm_gemm_l1<0, 2>(X0, H10, ha, WL1, wa, acc);
    i32x4 bq[4]; ldb4q(wb2, 2, bq);
    lstm_update_i8<0, false>(acc, cst1, bl1, dq1, 2.f, H11, QBUF, w, l16, grp, out0, b0, 0);
    __syncthreads();
    zacc_i(acc);
    lstm_gemm_i8<2, 4>(X0, H11, ha, wb2, bq, acc);
    lstm_update_i8<1, false>(acc, cst2, bl2, dq2, 1.f, X1, QBUF, w, l16, grp, out0, b0, 0);
    __syncthreads();
  }
  for (int t = 1; t < 31; ++t) {
    const char* Xr = (t & 1) ? X1 : X0;
    char*       Xw = (t & 1) ? X0 : X1;
    const char* Hr = (t & 1) ? H11 : H10;
    char*       Hw = (t & 1) ? H10 : H11;
    i32x4 acc[4][4]; zacc_i(acc);
    lstm_gemm_l1<0, 4>(Xr, Hr, ha, WL1, wa, acc);
    i32x4 bq[4]; ldb4q(wb2, 0, bq);
    lstm_update_i8<0, false>(acc, cst1, bl1, dq1, 1.f, Hw, QBUF, w, l16, grp, out0, b0, t);
    __syncthreads();
    zacc_i(acc);
    lstm_gemm_i8<0, 4>(Xr, Hw, ha, wb2, bq, acc);
    lstm_update_i8<1, false>(acc, cst2, bl2, dq2, 1.f, Xw, QBUF, w, l16, grp, out0, b0, t);
    __syncthreads();
  }
  { // t = 31 (odd): layer2 writes h2 as bf16 into QBUF (aliases WL1 - dead now).
    i32x4 acc[4][4]; zacc_i(acc);
    lstm_gemm_l1<0, 4>(X1, H11, ha, WL1, wa, acc);   // last WL1 use
    i32x4 bq[4]; ldb4q(wb2, 0, bq);
    lstm_update_i8<0, false>(acc, cst1, bl1, dq1, 1.f, H10, QBUF, w, l16, grp, out0, b0, 31);
    __syncthreads();                                 // all WL1 reads complete
    zacc_i(acc);
    lstm_gemm_i8<0, 4>(X1, H10, ha, wb2, bq, acc);
    lstm_update_i8<1, true>(acc, cst2, bl2, dq2, 1.f, X0, QBUF, w, l16, grp, out0, b0, 31);
    __syncthreads();
  }

  // ---- rebuild ctx (bf16) in CTX2 from registers ----
#pragma unroll
  for (int it = 0; it < 2; ++it) {
    int tile = w + it * 8;
    int mt = tile & 3, nt = tile >> 2;
    int n = nt * 16 + l16;
#pragma unroll
    for (int r = 0; r < 4; ++r) {
      int m = mt * 16 + grp * 4 + r;
      *(u16*)(CTX2 + m * 128 + ((((n >> 3) + m) & 7) << 4) + (n & 7) * 2) = f2bf(ctx3[it][r]);
    }
  }
  __syncthreads();

  // ---- quality L1: q_in = [h2_final(QBUF) | ctx(CTX2)], K=192 -> QL1 ----
  int hb[4][4];
#pragma unroll
  for (int mt = 0; mt < 4; ++mt) {
    int row = mt * 16 + l16;
#pragma unroll
    for (int k4 = 0; k4 < 4; ++k4)
      hb[mt][k4] = row * 256 + (((k4 * 4 + grp + row) & 15) << 4);
  }
#pragma unroll
  for (int it = 0; it < 4; ++it) {
    int tile = w + it * 8;
    int mt = tile & 3, nt = tile >> 2;
    int row = mt * 16 + l16;
    const u16* wl = wsb + OWQ1 + (size_t)(nt * 16 + l16) * 256 + grp * 8;
    f32x4 acc = (f32x4){0.f, 0.f, 0.f, 0.f};
#pragma unroll
    for (int kt = 0; kt < 4; ++kt) {
      s16x8 a = *(const s16x8*)(QBUF + hb[mt][kt]);
      s16x8 b = *(const s16x8*)(wl + kt * 32);
      acc = __builtin_amdgcn_mfma_f32_16x16x32_bf16(a, b, acc, 0, 0, 0);
    }
#pragma unroll
    for (int kc = 0; kc < 2; ++kc) {
      s16x8 a = *(const s16x8*)(CTX2 + row * 128 + (((kc * 4 + grp + row) & 7) << 4));
      s16x8 b = *(const s16x8*)(wl + (4 + kc) * 32);
      acc = __builtin_amdgcn_mfma_f32_16x16x32_bf16(a, b, acc, 0, 0, 0);
    }
    int n = nt * 16 + l16;
    float bias = P.bq1[n];
#pragma unroll
    for (int r = 0; r < 4; ++r)
      lds_wr_bf16(QL1, 256, 15, mt * 16 + grp * 4 + r, n, fmaxf(acc[r] + bias, 0.f));
  }
  __syncthreads();

  // ---- quality L2: (64x128)@Wq2^T -> relu -> QL2 (stride 128) ----
  gemm_generic<128, 256, 15, 16>(QL1, wsb + OWQ2, w, l16, grp,
    [&](int, int mt, int nt, f32x4 a) {
      int n = nt * 16 + l16;
      float bias = P.bq2[n];
#pragma unroll
      for (int r = 0; r < 4; ++r)
        lds_wr_bf16(QL2, 128, 7, mt * 16 + grp * 4 + r, n, fmaxf(a[r] + bias, 0.f));
    });
  __syncthreads();

  {  // q3: per-row dot(64) + sigmoid
    int m = tid >> 3, k8 = (tid & 7) * 8;
    int slot = ((k8 >> 3) + m) & 7;
    s16x8 qv = *(const s16x8*)(QL2 + m * 128 + (slot << 4));
    float s = 0.f;
#pragma unroll
    for (int i = 0; i < 8; ++i) s += bf2f((u16)qv[i]) * P.Wq3[k8 + i];
    s += __shfl_xor(s, 1); s += __shfl_xor(s, 2); s += __shfl_xor(s, 4);
    if ((lane & 7) == 0) out1[b0 + m] = sigf(s + P.bq3[0]);
  }
}

// ---------------------------------------------------------------------------
extern "C" void kernel_launch(void* const* d_in, const int* in_sizes, int n_in,
                              void* d_out, int out_size, void* d_ws, size_t ws_size,
                              hipStream_t stream) {
  (void)in_sizes; (void)n_in; (void)out_size; (void)ws_size;
  KParams P;
  P.gc   = (const float*)d_in[0];
  // d_in[1] = sequence_length (always 32)
  P.W1   = (const float*)d_in[2];  P.b1   = (const float*)d_in[3];
  P.W2   = (const float*)d_in[4];  P.b2   = (const float*)d_in[5];
  P.W3   = (const float*)d_in[6];  P.b3   = (const float*)d_in[7];
  P.Wih1 = (const float*)d_in[8];  P.bih1 = (const float*)d_in[9];
  P.Whh1 = (const float*)d_in[10]; P.bhh1 = (const float*)d_in[11];
  P.Wih2 = (const float*)d_in[12]; P.bih2 = (const float*)d_in[13];
  P.Whh2 = (const float*)d_in[14]; P.bhh2 = (const float*)d_in[15];
  P.Wq1  = (const float*)d_in[16]; P.bq1  = (const float*)d_in[17];
  P.Wq2  = (const float*)d_in[18]; P.bq2  = (const float*)d_in[19];
  P.Wq3  = (const float*)d_in[20]; P.bq3  = (const float*)d_in[21];
  P.Wp1  = (const float*)d_in[22]; P.bp1  = (const float*)d_in[23];
  P.Wp2  = (const float*)d_in[24]; P.bp2  = (const float*)d_in[25];
  P.Wd1  = (const float*)d_in[26]; P.bd1  = (const float*)d_in[27];
  P.Wd2  = (const float*)d_in[28]; P.bd2  = (const float*)d_in[29];
  P.Wc1  = (const float*)d_in[30]; P.bc1  = (const float*)d_in[31];
  P.Wc2  = (const float*)d_in[32]; P.bc2  = (const float*)d_in[33];

  u16*   wsb     = (u16*)d_ws;
  char*  wsbytes = (char*)d_ws;
  float* wsf     = (float*)((char*)d_ws + OFP32_B);

  prep_bf16<<<483, 256, 0, stream>>>(P, wsb, wsf);
  prep_lstm_q<<<1024, 64, 0, stream>>>(P, wsbytes, wsf);
  planning_fused<<<256, 512, 0, stream>>>(P, wsb, wsbytes, wsf, (float*)d_out);
}